// Round 8
// baseline (234.764 us; speedup 1.0000x reference)
//
#include <hip/hip_runtime.h>

#define IN_F   1024
#define OUT_F  1024
#define BATCHN 4096
#define KDIM   9216   // 9 * 1024 (t-plane layout: k = t*1024 + i)

using bf16x8 = __attribute__((ext_vector_type(8))) __bf16;
using f32x4  = __attribute__((ext_vector_type(4))) float;

__device__ __forceinline__ unsigned short f2bf(float f) {
  union { float f; unsigned int u; } v; v.f = f;
  unsigned int u = v.u;
  unsigned int r = (u + 0x7FFFu + ((u >> 16) & 1u)) >> 16;  // RNE
  return (unsigned short)r;
}

__device__ __forceinline__ float bf2f(unsigned short h) {
  union { unsigned int u; float f; } v; v.u = ((unsigned int)h) << 16;
  return v.f;
}

__device__ __forceinline__ void async_load16(const void* g, void* l) {
  __builtin_amdgcn_global_load_lds(
      (__attribute__((address_space(1))) void*)(g),
      (__attribute__((address_space(3))) void*)(l),
      16, 0, 0);
}

// ---------------------------------------------------------------------------
// Ã[b][t*1024+i] : t=0 -> silu(x[b,i]); t=1..8 -> cubic B-spline basis values
// ---------------------------------------------------------------------------
__global__ __launch_bounds__(256) void kan_prep_a(const float* __restrict__ x,
                                                  const float* __restrict__ grid,
                                                  unsigned short* __restrict__ A) {
  int idx = blockIdx.x * 256 + threadIdx.x;      // b*1024 + i, i fastest
  int i = idx & 1023;
  float xv = x[idx];
  float sil = xv / (1.0f + __expf(-xv));

  const float* g = grid + i * 12;
  float t[12];
#pragma unroll
  for (int j = 0; j < 12; ++j) t[j] = g[j];

  float B[11];
#pragma unroll
  for (int j = 0; j < 11; ++j) B[j] = (xv >= t[j] && xv < t[j + 1]) ? 1.0f : 0.0f;

  float inv_h = 1.0f / (t[4] - t[3]);            // uniform spacing
  const float invp[3] = {inv_h, inv_h * 0.5f, inv_h * (1.0f / 3.0f)};
#pragma unroll
  for (int p = 1; p <= 3; ++p) {
    float ip = invp[p - 1];
#pragma unroll
    for (int j = 0; j + p < 11; ++j)
      B[j] = (xv - t[j]) * ip * B[j] + (t[j + p + 1] - xv) * ip * B[j + 1];
  }

  size_t base = (size_t)(idx >> 10) * KDIM + i;
  A[base] = f2bf(sil);                            // t = 0 plane
#pragma unroll
  for (int k = 0; k < 8; ++k) A[base + (size_t)(k + 1) * 1024] = f2bf(B[k]);
}

// ---------------------------------------------------------------------------
// W_T[o][t*1024+i] = t==0 ? scale_base[i,o] : scale_sp[i,o]*coef[i,o,t-1]
// ---------------------------------------------------------------------------
__global__ __launch_bounds__(256) void kan_prep_w(const float* __restrict__ sb,
                                                  const float* __restrict__ ssp,
                                                  const float* __restrict__ coef,
                                                  unsigned short* __restrict__ WT) {
  __shared__ unsigned short lds[9][32][33];
  int i0 = (blockIdx.x >> 5) * 32, o0 = (blockIdx.x & 31) * 32;
  int tid = threadIdx.x;
#pragma unroll
  for (int r = 0; r < 4; ++r) {
    int idx = r * 256 + tid;
    int ii = idx >> 5, oo = idx & 31;
    int io = (i0 + ii) * 1024 + (o0 + oo);
    float b = sb[io], s = ssp[io];
    const float4* cp = (const float4*)(coef + (size_t)io * 8);
    float4 c0 = cp[0], c1 = cp[1];
    lds[0][ii][oo] = f2bf(b);
    lds[1][ii][oo] = f2bf(s * c0.x);
    lds[2][ii][oo] = f2bf(s * c0.y);
    lds[3][ii][oo] = f2bf(s * c0.z);
    lds[4][ii][oo] = f2bf(s * c0.w);
    lds[5][ii][oo] = f2bf(s * c1.x);
    lds[6][ii][oo] = f2bf(s * c1.y);
    lds[7][ii][oo] = f2bf(s * c1.z);
    lds[8][ii][oo] = f2bf(s * c1.w);
  }
  __syncthreads();
#pragma unroll
  for (int r = 0; r < 4; ++r) {
    int idx = r * 256 + tid;
    int oo = idx >> 5, ii = idx & 31;
    size_t rowbase = (size_t)(o0 + oo) * KDIM + i0 + ii;
#pragma unroll
    for (int tp = 0; tp < 9; ++tp) WT[rowbase + tp * 1024] = lds[tp][ii][oo];
  }
}

// ---------------------------------------------------------------------------
// GEMM split-K=4, A-via-LDS (ring-3) + B-direct-to-registers (L2-resident).
// BM=256 BN=256 BK=64, 512 thr / 8 waves (2Mx4N, 128x64 out per wave).
// LDS 96 KiB (A only). Per slice: vmcnt(4) -> barrier -> issue B(t+1)[8 glob
// dwordx4 -> reg set] + stage A(t+2)[4 gload_lds] -> 16 ds_read_b128 A-frags
// -> 64 MFMA (setprio). FIFO proof: the 4 newest outstanding loads are
// always the last A-stage; B(t) and A(t+1) are strictly older -> vmcnt(4)
// guarantees both. LDS port/slice ~1792 cyc < MFMA 2483 -> MFMA-bound.
// ---------------------------------------------------------------------------
#define BM 256
#define BN 256
#define BK 64
#define KQ     (KDIM / 4)    // 2304 per split-K group
#define NSL    (KQ / BK)     // 36
#define A_SLOT (BM * BK)     // 16384 elems = 32 KiB

__global__ __launch_bounds__(512, 2) void kan_gemm(const unsigned short* __restrict__ A,
                                                   const unsigned short* __restrict__ BT,
                                                   float* __restrict__ C,
                                                   unsigned short* __restrict__ P) {
  extern __shared__ unsigned short lds[];
  unsigned short* As = lds;                 // 3 * A_SLOT
  const int tid = threadIdx.x;
  const int wid = tid >> 6, lane = tid & 63;
  const int wr = wid >> 2, wc = wid & 3;    // 2x4 wave grid -> 128x64 per wave
  const int row16 = lane & 15, kgrp = lane >> 4;
  const int rsw = (row16 & 7) << 3;         // elem-space read swizzle

  // XCD swizzle: 256 blocks; XCD x owns wg in [32x,32x+32): fixed s, 8 m, 4 n
  int wg = ((blockIdx.x & 7) << 5) | (blockIdx.x >> 3);
  const int s = wg >> 6;
  const int m0 = ((wg >> 2) & 15) * BM, n0 = (wg & 3) * BN;
  const size_t ldb = (size_t)KDIM * 2;
  const size_t kbase = (size_t)s * (KQ * 2);
  const char* Ab = (const char*)A;

  // Per-lane B row base (elems): row = n0 + wc*64 + n*16 + row16, k = s*KQ + kgrp*8
  const unsigned short* Bl = BT + (size_t)(n0 + wc * 64 + row16) * KDIM
                           + (size_t)s * KQ + kgrp * 8;

  f32x4 acc[8][4] = {};

  auto stageA = [&](unsigned short* slotp, int sl) {
    size_t kbyte = kbase + (size_t)sl * (BK * 2);
#pragma unroll
    for (int q = 0; q < 4; ++q) {           // 32 KiB: 512 thr x 16B x 4
      int d = q * 8192 + tid * 16;
      int row = d >> 7;                     // 128 B per panel row
      int csw = (d & 127) ^ ((row & 7) << 4);
      async_load16(Ab + (size_t)(m0 + row) * ldb + kbyte + csw,
                   (char*)slotp + (q * 8192 + wid * 1024));
    }
  };
  auto loadB = [&](bf16x8 (&dst)[8], int sl) {
#pragma unroll
    for (int ks = 0; ks < 2; ++ks)
#pragma unroll
      for (int n = 0; n < 4; ++n)
        dst[ks * 4 + n] = *(const bf16x8*)(Bl + (size_t)(n * 16) * KDIM
                                              + (size_t)sl * BK + ks * 32);
  };

  auto slice = [&](int t, bf16x8 (&bC)[8], bf16x8 (&bN)[8], int slotCur, int slotN2) {
    if (t == NSL - 1) asm volatile("s_waitcnt vmcnt(0)" ::: "memory");
    else              asm volatile("s_waitcnt vmcnt(4)" ::: "memory");
    __builtin_amdgcn_sched_barrier(0);
    __builtin_amdgcn_s_barrier();
    if (t + 1 < NSL) loadB(bN, t + 1);                  // 8 global dwordx4
    if (t + 2 < NSL) stageA(As + slotN2 * A_SLOT, t + 2); // 4 gload_lds
    const unsigned short* as = As + slotCur * A_SLOT;
#pragma unroll
    for (int ks = 0; ks < 2; ++ks) {
      bf16x8 af[8];
      const int cb = (ks * 32 + kgrp * 8) ^ rsw;
#pragma unroll
      for (int m = 0; m < 8; ++m)
        af[m] = *(const bf16x8*)(as + (wr * 128 + m * 16 + row16) * BK + cb);
      __builtin_amdgcn_s_setprio(1);
#pragma unroll
      for (int m = 0; m < 8; ++m)
#pragma unroll
        for (int n = 0; n < 4; ++n)
          acc[m][n] = __builtin_amdgcn_mfma_f32_16x16x32_bf16(af[m], bC[ks * 4 + n],
                                                              acc[m][n], 0, 0, 0);
      __builtin_amdgcn_s_setprio(0);
    }
  };

  bf16x8 bA[8], bB[8];
  // Prologue FIFO: A(0)[4] B(0)[8] A(1)[4] -> slice0 vmcnt(4) leaves A(1)
  stageA(As, 0);
  loadB(bA, 0);
  stageA(As + A_SLOT, 1);

  int s0 = 0, s2 = 2;                        // slotCur, slot for t+2
  for (int t = 0; t < NSL; t += 2) {
    slice(t, bA, bB, s0, s2);
    int s1 = s0 + 1; if (s1 == 3) s1 = 0;
    int s3 = s2 + 1; if (s3 == 3) s3 = 0;
    slice(t + 1, bB, bA, s1, s3);
    s0 = s1 + 1; if (s0 == 3) s0 = 0;
    s2 = s3 + 1; if (s2 == 3) s2 = 0;
  }

  if (s == 3) {
    float* Cb = C + (size_t)(m0 + wr * 128) * OUT_F + n0 + wc * 64;
#pragma unroll
    for (int m = 0; m < 8; ++m)
#pragma unroll
      for (int n = 0; n < 4; ++n)
#pragma unroll
        for (int r = 0; r < 4; ++r)
          Cb[(size_t)(m * 16 + kgrp * 4 + r) * OUT_F + n * 16 + row16] = acc[m][n][r];
  } else {
    unsigned short* Pb = P + (size_t)s * BATCHN * OUT_F
                       + (size_t)(m0 + wr * 128) * OUT_F + n0 + wc * 64;
#pragma unroll
    for (int m = 0; m < 8; ++m)
#pragma unroll
      for (int n = 0; n < 4; ++n)
#pragma unroll
        for (int r = 0; r < 4; ++r)
          Pb[(size_t)(m * 16 + kgrp * 4 + r) * OUT_F + n * 16 + row16] = f2bf(acc[m][n][r]);
  }
}

// ---------------------------------------------------------------------------
// Merge split-K partials (3x bf16) + LayerNorm over last dim (1024), in-place.
// ---------------------------------------------------------------------------
__global__ __launch_bounds__(256) void kan_ln(float* __restrict__ y,
                                              const unsigned short* __restrict__ P,
                                              const float* __restrict__ gamma,
                                              const float* __restrict__ beta) {
  __shared__ float ss[4], ssq[4];
  int tid = threadIdx.x;
  float4* p = (float4*)(y + (size_t)blockIdx.x * OUT_F);
  float4 v = p[tid];
#pragma unroll
  for (int pp = 0; pp < 3; ++pp) {
    const ushort4 pv = ((const ushort4*)(P + (size_t)pp * BATCHN * OUT_F
                                           + (size_t)blockIdx.x * OUT_F))[tid];
    v.x += bf2f(pv.x);
    v.y += bf2f(pv.y);
    v.z += bf2f(pv.z);
    v.w += bf2f(pv.w);
  }
  float s = v.x + v.y + v.z + v.w;
  float q = v.x * v.x + v.y * v.y + v.z * v.z + v.w * v.w;
#pragma unroll
  for (int off = 1; off < 64; off <<= 1) {
    s += __shfl_xor(s, off);
    q += __shfl_xor(q, off);
  }
  if ((tid & 63) == 0) { ss[tid >> 6] = s; ssq[tid >> 6] = q; }
  __syncthreads();
  float S = ss[0] + ss[1] + ss[2] + ss[3];
  float Q = ssq[0] + ssq[1] + ssq[2] + ssq[3];
  float mu  = S * (1.0f / OUT_F);
  float var = Q * (1.0f / OUT_F) - mu * mu;
  float inv = rsqrtf(var + 1e-5f);
  const float4 g  = ((const float4*)gamma)[tid];
  const float4 bt = ((const float4*)beta)[tid];
  float4 o;
  o.x = (v.x - mu) * inv * g.x + bt.x;
  o.y = (v.y - mu) * inv * g.y + bt.y;
  o.z = (v.z - mu) * inv * g.z + bt.z;
  o.w = (v.w - mu) * inv * g.w + bt.w;
  p[tid] = o;
}

extern "C" void kernel_launch(void* const* d_in, const int* in_sizes, int n_in,
                              void* d_out, int out_size, void* d_ws, size_t ws_size,
                              hipStream_t stream) {
  const float* x     = (const float*)d_in[0];
  const float* coef  = (const float*)d_in[1];
  const float* sb    = (const float*)d_in[2];
  const float* ssp   = (const float*)d_in[3];
  const float* gamma = (const float*)d_in[4];
  const float* beta  = (const float*)d_in[5];
  const float* grid  = (const float*)d_in[6];

  const size_t a_elems  = (size_t)BATCHN * KDIM;       // 75.5 MB bf16
  const size_t wt_elems = (size_t)OUT_F * KDIM;        // 18.9 MB bf16
  const size_t p_elems  = (size_t)3 * BATCHN * OUT_F;  // 25.2 MB bf16
  if (ws_size < (a_elems + wt_elems + p_elems) * sizeof(unsigned short)) return;

  unsigned short* A  = (unsigned short*)d_ws;
  unsigned short* WT = A + a_elems;
  unsigned short* P  = WT + wt_elems;
  float* y = (float*)d_out;

  const size_t lds_bytes = 3 * (size_t)A_SLOT * sizeof(unsigned short); // 96 KiB
  static bool attr_set = false;
  if (!attr_set) {
    hipFuncSetAttribute((const void*)kan_gemm,
                        hipFuncAttributeMaxDynamicSharedMemorySize, (int)lds_bytes);
    attr_set = true;
  }

  kan_prep_a<<<dim3((BATCHN * IN_F) / 256), dim3(256), 0, stream>>>(x, grid, A);
  kan_prep_w<<<dim3((IN_F / 32) * (OUT_F / 32)), dim3(256), 0, stream>>>(sb, ssp, coef, WT);
  kan_gemm<<<dim3(4 * (BATCHN / BM) * (OUT_F / BN)), dim3(512), lds_bytes, stream>>>(A, WT, y, P);
  kan_ln<<<dim3(BATCHN), dim3(256), 0, stream>>>(y, P, gamma, beta);
}

// Round 9
// 113.139 us; speedup vs baseline: 2.0750x; 2.0750x over previous
//
#include <hip/hip_runtime.h>

#define IN_F   1024
#define OUT_F  1024
#define BATCHN 4096
#define KDIM   9216   // 9 * 1024 (t-plane layout: k = t*1024 + i)

using bf16x8 = __attribute__((ext_vector_type(8))) __bf16;
using f32x4  = __attribute__((ext_vector_type(4))) float;

__device__ __forceinline__ unsigned short f2bf(float f) {
  union { float f; unsigned int u; } v; v.f = f;
  unsigned int u = v.u;
  unsigned int r = (u + 0x7FFFu + ((u >> 16) & 1u)) >> 16;  // RNE
  return (unsigned short)r;
}

__device__ __forceinline__ float bf2f(unsigned short h) {
  union { unsigned int u; float f; } v; v.u = ((unsigned int)h) << 16;
  return v.f;
}

__device__ __forceinline__ void async_load16(const void* g, void* l) {
  __builtin_amdgcn_global_load_lds(
      (__attribute__((address_space(1))) void*)(g),
      (__attribute__((address_space(3))) void*)(l),
      16, 0, 0);
}

// ---------------------------------------------------------------------------
// Ã[b][t*1024+i] : t=0 -> silu(x[b,i]); t=1..8 -> cubic B-spline basis values
// 4 elements per thread: float4 x-load, one grid row (rows identical by
// construction), ushort4 plane stores.
// ---------------------------------------------------------------------------
__global__ __launch_bounds__(256) void kan_prep_a(const float* __restrict__ x,
                                                  const float* __restrict__ grid,
                                                  unsigned short* __restrict__ A) {
  int idx4 = blockIdx.x * 256 + threadIdx.x;     // one thread = 4 consecutive i
  int b  = idx4 >> 8;
  int i0 = (idx4 & 255) * 4;

  const float4 xv4 = *(const float4*)(x + (size_t)b * IN_F + i0);
  const float4* gp = (const float4*)grid;         // row 0 == all rows
  float4 g0 = gp[0], g1 = gp[1], g2 = gp[2];
  float t[12] = {g0.x, g0.y, g0.z, g0.w, g1.x, g1.y, g1.z, g1.w,
                 g2.x, g2.y, g2.z, g2.w};

  float inv_h = 1.0f / (t[4] - t[3]);             // uniform spacing
  const float invp[3] = {inv_h, inv_h * 0.5f, inv_h * (1.0f / 3.0f)};

  float xs[4] = {xv4.x, xv4.y, xv4.z, xv4.w};
  unsigned short o[9][4];

#pragma unroll
  for (int e = 0; e < 4; ++e) {
    float xv = xs[e];
    float sil = xv / (1.0f + __expf(-xv));
    float B[11];
#pragma unroll
    for (int j = 0; j < 11; ++j) B[j] = (xv >= t[j] && xv < t[j + 1]) ? 1.0f : 0.0f;
#pragma unroll
    for (int p = 1; p <= 3; ++p) {
      float ip = invp[p - 1];
#pragma unroll
      for (int j = 0; j + p < 11; ++j)
        B[j] = (xv - t[j]) * ip * B[j] + (t[j + p + 1] - xv) * ip * B[j + 1];
    }
    o[0][e] = f2bf(sil);
#pragma unroll
    for (int k = 0; k < 8; ++k) o[k + 1][e] = f2bf(B[k]);
  }

  size_t base = (size_t)b * KDIM + i0;
#pragma unroll
  for (int tp = 0; tp < 9; ++tp)
    *(ushort4*)(A + base + (size_t)tp * 1024) = *(const ushort4*)&o[tp][0];
}

// ---------------------------------------------------------------------------
// W_T[o][t*1024+i] = t==0 ? scale_base[i,o] : scale_sp[i,o]*coef[i,o,t-1]
// ---------------------------------------------------------------------------
__global__ __launch_bounds__(256) void kan_prep_w(const float* __restrict__ sb,
                                                  const float* __restrict__ ssp,
                                                  const float* __restrict__ coef,
                                                  unsigned short* __restrict__ WT) {
  __shared__ unsigned short lds[9][32][33];
  int i0 = (blockIdx.x >> 5) * 32, o0 = (blockIdx.x & 31) * 32;
  int tid = threadIdx.x;
#pragma unroll
  for (int r = 0; r < 4; ++r) {
    int idx = r * 256 + tid;
    int ii = idx >> 5, oo = idx & 31;
    int io = (i0 + ii) * 1024 + (o0 + oo);
    float b = sb[io], s = ssp[io];
    const float4* cp = (const float4*)(coef + (size_t)io * 8);
    float4 c0 = cp[0], c1 = cp[1];
    lds[0][ii][oo] = f2bf(b);
    lds[1][ii][oo] = f2bf(s * c0.x);
    lds[2][ii][oo] = f2bf(s * c0.y);
    lds[3][ii][oo] = f2bf(s * c0.z);
    lds[4][ii][oo] = f2bf(s * c0.w);
    lds[5][ii][oo] = f2bf(s * c1.x);
    lds[6][ii][oo] = f2bf(s * c1.y);
    lds[7][ii][oo] = f2bf(s * c1.z);
    lds[8][ii][oo] = f2bf(s * c1.w);
  }
  __syncthreads();
#pragma unroll
  for (int r = 0; r < 4; ++r) {
    int idx = r * 256 + tid;
    int oo = idx >> 5, ii = idx & 31;
    size_t rowbase = (size_t)(o0 + oo) * KDIM + i0 + ii;
#pragma unroll
    for (int tp = 0; tp < 9; ++tp) WT[rowbase + tp * 1024] = lds[tp][ii][oo];
  }
}

// ---------------------------------------------------------------------------
// GEMM split-K=4, counted-vmcnt ring + 4-phase fine interleave (r6, best).
// BM=256 BN=256 BK=64, 512 thr / 8 waves (2Mx4N, 128x64 out per wave).
// LDS 160 KiB: A ring-3 (2 ahead), B ring-2 (1 ahead).
// ---------------------------------------------------------------------------
#define BM 256
#define BN 256
#define BK 64
#define KQ     (KDIM / 4)    // 2304 per split-K group
#define NSL    (KQ / BK)     // 36
#define A_SLOT (BM * BK)     // 16384 elems = 32 KiB
#define B_SLOT (BN * BK)     // 16384 elems = 32 KiB

__global__ __launch_bounds__(512, 2) void kan_gemm(const unsigned short* __restrict__ A,
                                                   const unsigned short* __restrict__ BT,
                                                   float* __restrict__ C,
                                                   unsigned short* __restrict__ P) {
  extern __shared__ unsigned short lds[];
  unsigned short* As = lds;                 // 3 * A_SLOT
  unsigned short* Bs = lds + 3 * A_SLOT;    // 2 * B_SLOT
  const int tid = threadIdx.x;
  const int wid = tid >> 6, lane = tid & 63;
  const int wr = wid >> 2, wc = wid & 3;    // 2x4 wave grid -> 128x64 per wave
  const int row16 = lane & 15, kgrp = lane >> 4;
  const int rsw = (row16 & 7) << 3;         // elem-space read swizzle

  // XCD swizzle: 256 blocks; XCD x owns wg in [32x,32x+32): fixed s, 8 m, 4 n
  int wg = ((blockIdx.x & 7) << 5) | (blockIdx.x >> 3);
  const int s = wg >> 6;
  const int m0 = ((wg >> 2) & 15) * BM, n0 = (wg & 3) * BN;
  const size_t ldb = (size_t)KDIM * 2;
  const size_t kbase = (size_t)s * (KQ * 2);
  const char* Ab = (const char*)A;
  const char* Bb = (const char*)BT;

  f32x4 acc[8][4] = {};

  auto stage = [&](const char* Gb, int grow0, unsigned short* slotp, int sl) {
    size_t kbyte = kbase + (size_t)sl * (BK * 2);
#pragma unroll
    for (int q = 0; q < 4; ++q) {           // 32 KiB: 512 thr x 16B x 4
      int d = q * 8192 + tid * 16;
      int row = d >> 7;
      int csw = (d & 127) ^ ((row & 7) << 4);
      async_load16(Gb + (size_t)(grow0 + row) * ldb + kbyte + csw,
                   (char*)slotp + (q * 8192 + wid * 1024));
    }
  };

  // Prologue FIFO: A(0)[4] B(0)[4] A(1)[4] -> iter0 vmcnt(4) clears A(0),B(0)
  stage(Ab, m0, As, 0);
  stage(Bb, n0, Bs, 0);
  stage(Ab, m0, As + A_SLOT, 1);

  int consA = 0;                            // sl % 3
  for (int sl = 0; sl < NSL; ++sl) {
    if (sl < NSL - 1) asm volatile("s_waitcnt vmcnt(4)" ::: "memory");
    else              asm volatile("s_waitcnt vmcnt(0)" ::: "memory");
    __builtin_amdgcn_s_barrier();
    __builtin_amdgcn_sched_barrier(0);
    const unsigned short* as = As + consA * A_SLOT;
    const unsigned short* bs = Bs + (sl & 1) * B_SLOT;
    const int cb0 = (kgrp * 8) ^ rsw;       // ks=0
    const int cb1 = (32 + kgrp * 8) ^ rsw;  // ks=1

    // ---- phase 0: B(ks0) + A-low(ks0); stage B(sl+1) ----
    bf16x8 b0[4], a0[4];
#pragma unroll
    for (int n = 0; n < 4; ++n)
      b0[n] = *(const bf16x8*)(bs + (wc * 64 + n * 16 + row16) * BK + cb0);
#pragma unroll
    for (int m = 0; m < 4; ++m)
      a0[m] = *(const bf16x8*)(as + (wr * 128 + m * 16 + row16) * BK + cb0);
    if (sl + 1 < NSL) stage(Bb, n0, Bs + ((sl + 1) & 1) * B_SLOT, sl + 1);
    __builtin_amdgcn_sched_barrier(0);
    __builtin_amdgcn_s_barrier();
    __builtin_amdgcn_s_setprio(1);
#pragma unroll
    for (int m = 0; m < 4; ++m)
#pragma unroll
      for (int n = 0; n < 4; ++n)
        acc[m][n] = __builtin_amdgcn_mfma_f32_16x16x32_bf16(a0[m], b0[n], acc[m][n], 0, 0, 0);
    __builtin_amdgcn_s_setprio(0);

    // ---- phase 1: A-high(ks0); stage A(sl+2) ----
    bf16x8 a1[4];
#pragma unroll
    for (int m = 0; m < 4; ++m)
      a1[m] = *(const bf16x8*)(as + (wr * 128 + (m + 4) * 16 + row16) * BK + cb0);
    {
      int stgA = consA - 1; if (stgA < 0) stgA += 3;   // (sl+2) % 3
      if (sl + 2 < NSL) stage(Ab, m0, As + stgA * A_SLOT, sl + 2);
    }
    __builtin_amdgcn_sched_barrier(0);
    __builtin_amdgcn_s_barrier();
    __builtin_amdgcn_s_setprio(1);
#pragma unroll
    for (int m = 0; m < 4; ++m)
#pragma unroll
      for (int n = 0; n < 4; ++n)
        acc[m + 4][n] = __builtin_amdgcn_mfma_f32_16x16x32_bf16(a1[m], b0[n], acc[m + 4][n], 0, 0, 0);
    __builtin_amdgcn_s_setprio(0);

    // ---- phase 2: B(ks1) + A-low(ks1) ----
    bf16x8 b1[4], a2[4];
#pragma unroll
    for (int n = 0; n < 4; ++n)
      b1[n] = *(const bf16x8*)(bs + (wc * 64 + n * 16 + row16) * BK + cb1);
#pragma unroll
    for (int m = 0; m < 4; ++m)
      a2[m] = *(const bf16x8*)(as + (wr * 128 + m * 16 + row16) * BK + cb1);
    __builtin_amdgcn_sched_barrier(0);
    __builtin_amdgcn_s_barrier();
    __builtin_amdgcn_s_setprio(1);
#pragma unroll
    for (int m = 0; m < 4; ++m)
#pragma unroll
      for (int n = 0; n < 4; ++n)
        acc[m][n] = __builtin_amdgcn_mfma_f32_16x16x32_bf16(a2[m], b1[n], acc[m][n], 0, 0, 0);
    __builtin_amdgcn_s_setprio(0);

    // ---- phase 3: A-high(ks1) ----
    bf16x8 a3[4];
#pragma unroll
    for (int m = 0; m < 4; ++m)
      a3[m] = *(const bf16x8*)(as + (wr * 128 + (m + 4) * 16 + row16) * BK + cb1);
    __builtin_amdgcn_sched_barrier(0);
    __builtin_amdgcn_s_barrier();
    __builtin_amdgcn_s_setprio(1);
#pragma unroll
    for (int m = 0; m < 4; ++m)
#pragma unroll
      for (int n = 0; n < 4; ++n)
        acc[m + 4][n] = __builtin_amdgcn_mfma_f32_16x16x32_bf16(a3[m], b1[n], acc[m + 4][n], 0, 0, 0);
    __builtin_amdgcn_s_setprio(0);

    consA = (consA == 2) ? 0 : consA + 1;
  }

  if (s == 3) {
    float* Cb = C + (size_t)(m0 + wr * 128) * OUT_F + n0 + wc * 64;
#pragma unroll
    for (int m = 0; m < 8; ++m)
#pragma unroll
      for (int n = 0; n < 4; ++n)
#pragma unroll
        for (int r = 0; r < 4; ++r)
          Cb[(size_t)(m * 16 + kgrp * 4 + r) * OUT_F + n * 16 + row16] = acc[m][n][r];
  } else {
    unsigned short* Pb = P + (size_t)s * BATCHN * OUT_F
                       + (size_t)(m0 + wr * 128) * OUT_F + n0 + wc * 64;
#pragma unroll
    for (int m = 0; m < 8; ++m)
#pragma unroll
      for (int n = 0; n < 4; ++n)
#pragma unroll
        for (int r = 0; r < 4; ++r)
          Pb[(size_t)(m * 16 + kgrp * 4 + r) * OUT_F + n * 16 + row16] = f2bf(acc[m][n][r]);
  }
}

// ---------------------------------------------------------------------------
// Merge split-K partials (3x bf16) + LayerNorm over last dim (1024), in-place.
// ---------------------------------------------------------------------------
__global__ __launch_bounds__(256) void kan_ln(float* __restrict__ y,
                                              const unsigned short* __restrict__ P,
                                              const float* __restrict__ gamma,
                                              const float* __restrict__ beta) {
  __shared__ float ss[4], ssq[4];
  int tid = threadIdx.x;
  float4* p = (float4*)(y + (size_t)blockIdx.x * OUT_F);
  float4 v = p[tid];
#pragma unroll
  for (int pp = 0; pp < 3; ++pp) {
    const ushort4 pv = ((const ushort4*)(P + (size_t)pp * BATCHN * OUT_F
                                           + (size_t)blockIdx.x * OUT_F))[tid];
    v.x += bf2f(pv.x);
    v.y += bf2f(pv.y);
    v.z += bf2f(pv.z);
    v.w += bf2f(pv.w);
  }
  float s = v.x + v.y + v.z + v.w;
  float q = v.x * v.x + v.y * v.y + v.z * v.z + v.w * v.w;
#pragma unroll
  for (int off = 1; off < 64; off <<= 1) {
    s += __shfl_xor(s, off);
    q += __shfl_xor(q, off);
  }
  if ((tid & 63) == 0) { ss[tid >> 6] = s; ssq[tid >> 6] = q; }
  __syncthreads();
  float S = ss[0] + ss[1] + ss[2] + ss[3];
  float Q = ssq[0] + ssq[1] + ssq[2] + ssq[3];
  float mu  = S * (1.0f / OUT_F);
  float var = Q * (1.0f / OUT_F) - mu * mu;
  float inv = rsqrtf(var + 1e-5f);
  const float4 g  = ((const float4*)gamma)[tid];
  const float4 bt = ((const float4*)beta)[tid];
  float4 o;
  o.x = (v.x - mu) * inv * g.x + bt.x;
  o.y = (v.y - mu) * inv * g.y + bt.y;
  o.z = (v.z - mu) * inv * g.z + bt.z;
  o.w = (v.w - mu) * inv * g.w + bt.w;
  p[tid] = o;
}

extern "C" void kernel_launch(void* const* d_in, const int* in_sizes, int n_in,
                              void* d_out, int out_size, void* d_ws, size_t ws_size,
                              hipStream_t stream) {
  const float* x     = (const float*)d_in[0];
  const float* coef  = (const float*)d_in[1];
  const float* sb    = (const float*)d_in[2];
  const float* ssp   = (const float*)d_in[3];
  const float* gamma = (const float*)d_in[4];
  const float* beta  = (const float*)d_in[5];
  const float* grid  = (const float*)d_in[6];

  const size_t a_elems  = (size_t)BATCHN * KDIM;       // 75.5 MB bf16
  const size_t wt_elems = (size_t)OUT_F * KDIM;        // 18.9 MB bf16
  const size_t p_elems  = (size_t)3 * BATCHN * OUT_F;  // 25.2 MB bf16
  if (ws_size < (a_elems + wt_elems + p_elems) * sizeof(unsigned short)) return;

  unsigned short* A  = (unsigned short*)d_ws;
  unsigned short* WT = A + a_elems;
  unsigned short* P  = WT + wt_elems;
  float* y = (float*)d_out;

  const size_t lds_bytes = (3 * (size_t)A_SLOT + 2 * (size_t)B_SLOT) * sizeof(unsigned short); // 160 KiB
  static bool attr_set = false;
  if (!attr_set) {
    hipFuncSetAttribute((const void*)kan_gemm,
                        hipFuncAttributeMaxDynamicSharedMemorySize, (int)lds_bytes);
    attr_set = true;
  }

  kan_prep_a<<<dim3((BATCHN * IN_F) / 1024), dim3(256), 0, stream>>>(x, grid, A);
  kan_prep_w<<<dim3((IN_F / 32) * (OUT_F / 32)), dim3(256), 0, stream>>>(sb, ssp, coef, WT);
  kan_gemm<<<dim3(4 * (BATCHN / BM) * (OUT_F / BN)), dim3(512), lds_bytes, stream>>>(A, WT, y, P);
  kan_ln<<<dim3(BATCHN), dim3(256), 0, stream>>>(y, P, gamma, beta);
}